// Round 1
// baseline (62826.855 us; speedup 1.0000x reference)
//
#include <hip/hip_runtime.h>
#include <hip/hip_cooperative_groups.h>
#include <math.h>

namespace cg = cooperative_groups;

#define NH 1024
#define NB 32
#define NT 512

// ws layout (floats):
// [0,      32768)   hT0 buf0   (h0 state, parity-0 read buffer; holds h0 init)
// [32768,  65536)   hT0 buf1
// [65536,  98304)   hT1 buf0
// [98304, 131072)   hT1 buf1   (holds h1 init; first layer-1 read is at s=1, parity 1)
// [131072,139264)   plog[128][64]  per-L1-block logit partials

__global__ __launch_bounds__(256) void init_kernel(const float* __restrict__ h0,
                                                   float* __restrict__ ws) {
  int g = blockIdx.x * 256 + threadIdx.x;  // 0..65535  == l*32768 + b*1024 + k
  int l = g >> 15;
  int b = (g >> 10) & 31;
  int k = g & 1023;
  size_t base = l ? (size_t)98304 : (size_t)0;  // h0 -> hT0 buf0, h1 -> hT1 buf1
  ws[base + (size_t)k * 32 + b] = h0[g];
}

__global__ __launch_bounds__(512, 1) void rnn_kernel(
    const float* __restrict__ x,
    const float* __restrict__ Wih0, const float* __restrict__ Whh0,
    const float* __restrict__ bih0, const float* __restrict__ bhh0,
    const float* __restrict__ Wih1, const float* __restrict__ Whh1,
    const float* __restrict__ bih1, const float* __restrict__ bhh1,
    const float* __restrict__ Wcls, const float* __restrict__ bcls,
    float* __restrict__ out, float* ws) {
  cg::grid_group grid = cg::this_grid();

  const int bid = blockIdx.x;       // 0..255
  const int tid = threadIdx.x;      // 0..511
  const int b   = tid & 31;         // batch lane
  const int jg  = (tid >> 5) & 7;   // column within block's 8-col slice
  const int kh  = tid >> 8;         // K-half: 0 or 1
  const bool isL1 = (bid >= 128);
  const int j = (isL1 ? (bid - 128) : bid) * 8 + jg;

  float* hT0buf[2] = { ws,          ws + 32768 };
  float* hT1buf[2] = { ws + 65536,  ws + 98304 };
  float* plog = ws + 131072;

  __shared__ float part[8][33];
  __shared__ float lred[2][8][32];

  // Per-thread constant setup: which weight row this (j, kh) uses, and bias.
  float bias;
  const float4* wrow;
  if (!isL1) {
    bias = bih0[j] + bhh0[j];
    wrow = (const float4*)((kh == 0 ? Wih0 : Whh0) + (size_t)j * NH);
  } else {
    bias = bih1[j] + bhh1[j];
    wrow = (const float4*)((kh == 0 ? Wih1 : Whh1) + (size_t)j * NH);
  }

  float lg0 = 0.f, lg1 = 0.f;  // per-thread classifier partials (L1, kh==0)

  for (int s = 0; s <= NT; ++s) {
    const int rp = s & 1;
    const bool active = isL1 ? (s >= 1) : (s < NT);
    if (active) {
      float a0 = 0.f, a1 = 0.f, a2 = 0.f, a3 = 0.f;
      if (!isL1 && kh == 0) {
        // layer 0, input half:  x[b,s,:] . Wih0[j,:]
        const float4* xr = (const float4*)(x + ((size_t)b * NT + s) * NH);
        #pragma unroll 4
        for (int q = 0; q < 256; q += 4) {
          float4 w0 = wrow[q+0], v0 = xr[q+0];
          float4 w1 = wrow[q+1], v1 = xr[q+1];
          float4 w2 = wrow[q+2], v2 = xr[q+2];
          float4 w3 = wrow[q+3], v3 = xr[q+3];
          a0=fmaf(w0.x,v0.x,a0); a0=fmaf(w0.y,v0.y,a0); a0=fmaf(w0.z,v0.z,a0); a0=fmaf(w0.w,v0.w,a0);
          a1=fmaf(w1.x,v1.x,a1); a1=fmaf(w1.y,v1.y,a1); a1=fmaf(w1.z,v1.z,a1); a1=fmaf(w1.w,v1.w,a1);
          a2=fmaf(w2.x,v2.x,a2); a2=fmaf(w2.y,v2.y,a2); a2=fmaf(w2.z,v2.z,a2); a2=fmaf(w2.w,v2.w,a2);
          a3=fmaf(w3.x,v3.x,a3); a3=fmaf(w3.y,v3.y,a3); a3=fmaf(w3.z,v3.z,a3); a3=fmaf(w3.w,v3.w,a3);
        }
      } else {
        // hidden-state half: h . W[j,:], h stored transposed hT[k][b]
        const float* hsrc;
        if (!isL1)          hsrc = hT0buf[rp];              // L0 kh==1: h0 . Whh0
        else if (kh == 0)   hsrc = hT0buf[rp];              // L1: y0 . Wih1
        else                hsrc = hT1buf[rp];              // L1: h1 . Whh1
        const float* hp = hsrc + b;
        #pragma unroll 4
        for (int q = 0; q < 256; q += 4) {
          float4 w0 = wrow[q+0];
          float4 w1 = wrow[q+1];
          float4 w2 = wrow[q+2];
          float4 w3 = wrow[q+3];
          const float* h0p = hp + (size_t)q * 128;  // k = q*4 -> offset q*4*32
          a0=fmaf(w0.x,h0p[  0],a0); a0=fmaf(w0.y,h0p[ 32],a0); a0=fmaf(w0.z,h0p[ 64],a0); a0=fmaf(w0.w,h0p[ 96],a0);
          a1=fmaf(w1.x,h0p[128],a1); a1=fmaf(w1.y,h0p[160],a1); a1=fmaf(w1.z,h0p[192],a1); a1=fmaf(w1.w,h0p[224],a1);
          a2=fmaf(w2.x,h0p[256],a2); a2=fmaf(w2.y,h0p[288],a2); a2=fmaf(w2.z,h0p[320],a2); a2=fmaf(w2.w,h0p[352],a2);
          a3=fmaf(w3.x,h0p[384],a3); a3=fmaf(w3.y,h0p[416],a3); a3=fmaf(w3.z,h0p[448],a3); a3=fmaf(w3.w,h0p[480],a3);
        }
      }
      float acc = (a0 + a1) + (a2 + a3);
      if (kh == 1) part[jg][b] = acc;
      __syncthreads();
      if (kh == 0) {
        float hv = tanhf(bias + acc + part[jg][b]);
        if (!isL1) {
          hT0buf[rp ^ 1][(size_t)j * 32 + b] = hv;
        } else {
          hT1buf[rp ^ 1][(size_t)j * 32 + b] = hv;
          const int t = s - 1;
          lg0 = fmaf(hv, Wcls[(size_t)t * NH + j], lg0);
          lg1 = fmaf(hv, Wcls[(size_t)524288 + (size_t)t * NH + j], lg1);
        }
      }
      __syncthreads();
    }
    __threadfence();
    grid.sync();
  }

  // ---- epilogue ----
  // h_n: each block writes back its own j-slice (own writes; no cross-block dep).
  // h0 final was written at s=511 into buf[(511+1)&1] = buf0.
  // h1 final was written at s=512 into buf[(512+1)&1] = buf1.
  if (kh == 0) {
    if (!isL1) {
      out[64 + (size_t)b * NH + j] = hT0buf[0][(size_t)j * 32 + b];
    } else {
      out[64 + 32768 + (size_t)b * NH + j] = hT1buf[1][(size_t)j * 32 + b];
      lred[0][jg][b] = lg0;
      lred[1][jg][b] = lg1;
    }
  }
  __syncthreads();
  if (isL1 && tid < 64) {
    const int c = tid >> 5, bb = tid & 31;
    float v = 0.f;
    #pragma unroll
    for (int g2 = 0; g2 < 8; ++g2) v += lred[c][g2][bb];
    plog[(size_t)(bid - 128) * 64 + c * 32 + bb] = v;
  }
  __threadfence();
  grid.sync();
  if (bid == 0 && tid < 64) {
    const int c = tid >> 5, bb = tid & 31;
    float v = bcls[c];
    for (int blk = 0; blk < 128; ++blk) v += plog[(size_t)blk * 64 + c * 32 + bb];
    out[(size_t)bb * 2 + c] = v;  // logits [B,C] row-major
  }
}

extern "C" void kernel_launch(void* const* d_in, const int* in_sizes, int n_in,
                              void* d_out, int out_size, void* d_ws, size_t ws_size,
                              hipStream_t stream) {
  const float* x    = (const float*)d_in[0];
  const float* h0   = (const float*)d_in[1];
  const float* Wih0 = (const float*)d_in[2];
  const float* Whh0 = (const float*)d_in[3];
  const float* bih0 = (const float*)d_in[4];
  const float* bhh0 = (const float*)d_in[5];
  const float* Wih1 = (const float*)d_in[6];
  const float* Whh1 = (const float*)d_in[7];
  const float* bih1 = (const float*)d_in[8];
  const float* bhh1 = (const float*)d_in[9];
  const float* Wcls = (const float*)d_in[10];
  const float* bcls = (const float*)d_in[11];
  float* out = (float*)d_out;
  float* ws  = (float*)d_ws;

  hipLaunchKernelGGL(init_kernel, dim3(256), dim3(256), 0, stream, h0, ws);

  void* args[] = { (void*)&x, (void*)&Wih0, (void*)&Whh0, (void*)&bih0, (void*)&bhh0,
                   (void*)&Wih1, (void*)&Whh1, (void*)&bih1, (void*)&bhh1,
                   (void*)&Wcls, (void*)&bcls, (void*)&out, (void*)&ws };
  hipLaunchCooperativeKernel((void*)rnn_kernel, dim3(256), dim3(512), args, 0, stream);
}

// Round 2
// 11511.832 us; speedup vs baseline: 5.4576x; 5.4576x over previous
//
#include <hip/hip_runtime.h>
#include <math.h>

typedef float f4 __attribute__((ext_vector_type(4)));

#define NT 512
#define NH 1024
#define NHQ 256   // NH/4

// ws float offsets
#define H00 0
#define H01 32768
#define H10 65536
#define H11 98304
#define PLOG 131072      // 8192 floats
#define CTRS 139264      // uint region: 8 ctrs at stride 32, master at +256
#define X4OFF 139776
#define X4FLOATS (512u * 1024u * 32u)  // 16,777,216 floats = 64 MB

__device__ __forceinline__ f4 ld_coh(const f4* p) {
  return *(const volatile f4*)p;   // gfx940+: volatile -> sc0 sc1 (MALL-coherent)
}
__device__ __forceinline__ void st_coh(float* p, float v) {
  __hip_atomic_store(p, v, __ATOMIC_RELAXED, __HIP_MEMORY_SCOPE_AGENT);
}
__device__ __forceinline__ float ld_cohf(const float* p) {
  return __hip_atomic_load(p, __ATOMIC_RELAXED, __HIP_MEMORY_SCOPE_AGENT);
}

__global__ __launch_bounds__(256) void init_kernel(const float* __restrict__ h0,
                                                   float* __restrict__ ws) {
  int g = blockIdx.x * 256 + threadIdx.x;  // 0..65535 == l*32768 + b*1024 + k
  int l = g >> 15;
  int b = (g >> 10) & 31;
  int k = g & 1023;
  size_t base = l ? (size_t)H11 : (size_t)H00;
  // h4 layout: float offset (k/4)*128 + b*4 + (k&3)
  ws[base + (size_t)(k >> 2) * 128 + b * 4 + (k & 3)] = h0[g];
  if (g < 8) ((unsigned*)(ws + CTRS))[g * 32] = 0u;
  if (g == 8) ((unsigned*)(ws + CTRS))[256] = 0u;
}

__global__ __launch_bounds__(256) void xpose_kernel(const float* __restrict__ x,
                                                    float* __restrict__ ws) {
  f4* x4 = (f4*)(ws + X4OFF);
  const f4* xs = (const f4*)x;
  int t = blockIdx.x;             // 0..511
  int kqq = threadIdx.x >> 5;     // 0..7
  int b = threadIdx.x & 31;
  for (int i = 0; i < 32; ++i) {
    int kq = kqq * 32 + i;        // 0..255
    f4 v = xs[((size_t)b * NT + t) * NHQ + kq];
    x4[((size_t)t * NHQ + kq) * 32 + b] = v;   // coalesced write
  }
}

__device__ __forceinline__ void gbar(unsigned* c1, unsigned* c2, int g, unsigned r) {
  __syncthreads();  // drains vmcnt for all waves' global stores before the add
  if (threadIdx.x == 0) {
    unsigned old = __hip_atomic_fetch_add(&c1[g * 32], 1u, __ATOMIC_RELAXED,
                                          __HIP_MEMORY_SCOPE_AGENT);
    if (old == 32u * r - 1u)
      __hip_atomic_fetch_add(c2, 1u, __ATOMIC_RELAXED, __HIP_MEMORY_SCOPE_AGENT);
    while (__hip_atomic_load(c2, __ATOMIC_RELAXED, __HIP_MEMORY_SCOPE_AGENT) < 8u * r)
      __builtin_amdgcn_s_sleep(1);
  }
  __syncthreads();
}

__global__ __launch_bounds__(512, 1) void rnn_kernel(
    const float* __restrict__ x,
    const float* __restrict__ Wih0, const float* __restrict__ Whh0,
    const float* __restrict__ bih0, const float* __restrict__ bhh0,
    const float* __restrict__ Wih1, const float* __restrict__ Whh1,
    const float* __restrict__ bih1, const float* __restrict__ bhh1,
    const float* __restrict__ Wcls, const float* __restrict__ bcls,
    float* __restrict__ out, float* ws, int use_x4) {
  const int bid = blockIdx.x;        // 0..255
  const int tid = threadIdx.x;       // 0..511
  const int b   = tid & 31;          // batch lane
  const int ks  = (tid >> 5) & 7;    // k-slice 0..7
  const int mh  = tid >> 8;          // matrix half: 0=input-side, 1=hidden-side
  const bool isL1 = (bid >= 128);
  const int jbase = (isL1 ? (bid - 128) : bid) * 8;

  f4* h0buf[2] = { (f4*)(ws + H00), (f4*)(ws + H01) };
  f4* h1buf[2] = { (f4*)(ws + H10), (f4*)(ws + H11) };
  float* plog = ws + PLOG;
  unsigned* c1 = (unsigned*)(ws + CTRS);
  unsigned* c2 = c1 + 256;
  const f4* x4p = (const f4*)(ws + X4OFF);
  const int g = bid & 7;

  __shared__ float part[4096];  // [slot 16][ji 8][b 32]

  // W row-group base for this thread's matrix half
  const f4* wbase;
  if (!isL1) wbase = (const f4*)(mh == 0 ? Wih0 : Whh0) + (size_t)jbase * NHQ;
  else       wbase = (const f4*)(mh == 0 ? Wih1 : Whh1) + (size_t)jbase * NHQ;

  // reduce-phase constants (tid < 256): thread (rj, b) owns output column j
  const int rj = tid >> 5;           // 0..7 (valid when tid<256)
  const int jout = jbase + rj;
  float bias = 0.f;
  if (tid < 256)
    bias = isL1 ? (bih1[jout] + bhh1[jout]) : (bih0[jout] + bhh0[jout]);

  float lg0 = 0.f, lg1 = 0.f;
  const int kq0 = ks * 32;

  for (int s = 0; s <= NT; ++s) {
    const int rp = s & 1;
    const bool active = isL1 ? (s >= 1) : (s < NT);
    if (active) {
      f4 acc[8];
      #pragma unroll
      for (int ji = 0; ji < 8; ++ji) acc[ji] = (f4)0.f;

      if (!isL1 && mh == 0) {
        if (use_x4) {
          const f4* sp = x4p + (size_t)s * 8192 + b;
          #pragma unroll 4
          for (int q = 0; q < 32; ++q) {
            f4 v = sp[(size_t)(kq0 + q) * 32];
            const f4* wb = wbase + kq0 + q;
            #pragma unroll
            for (int ji = 0; ji < 8; ++ji) acc[ji] += wb[(size_t)ji * NHQ] * v;
          }
        } else {
          const f4* sp = (const f4*)x + ((size_t)b * NT + s) * NHQ;
          #pragma unroll 4
          for (int q = 0; q < 32; ++q) {
            f4 v = sp[kq0 + q];
            const f4* wb = wbase + kq0 + q;
            #pragma unroll
            for (int ji = 0; ji < 8; ++ji) acc[ji] += wb[(size_t)ji * NHQ] * v;
          }
        }
      } else {
        const f4* hsrc;
        if (!isL1)        hsrc = h0buf[rp];   // L0 hidden: h0 . Whh0
        else if (mh == 0) hsrc = h0buf[rp];   // L1 input: y0 . Wih1
        else              hsrc = h1buf[rp];   // L1 hidden: h1 . Whh1
        const f4* sp = hsrc + b;
        #pragma unroll 4
        for (int q = 0; q < 32; ++q) {
          f4 v = ld_coh(sp + (size_t)(kq0 + q) * 32);
          const f4* wb = wbase + kq0 + q;
          #pragma unroll
          for (int ji = 0; ji < 8; ++ji) acc[ji] += wb[(size_t)ji * NHQ] * v;
        }
      }

      const int slot = mh * 8 + ks;  // 0..15
      #pragma unroll
      for (int ji = 0; ji < 8; ++ji)
        part[(slot * 8 + ji) * 32 + b] =
            (acc[ji][0] + acc[ji][1]) + (acc[ji][2] + acc[ji][3]);
      __syncthreads();

      if (tid < 256) {
        float sum = bias;
        #pragma unroll
        for (int r = 0; r < 16; ++r) sum += part[(r * 8 + rj) * 32 + b];
        float hv = tanhf(sum);
        float* dst = (float*)(isL1 ? h1buf[rp ^ 1] : h0buf[rp ^ 1]);
        st_coh(dst + (size_t)(jout >> 2) * 128 + b * 4 + (jout & 3), hv);
        if (isL1) {
          const int t = s - 1;
          lg0 = fmaf(hv, Wcls[(size_t)t * NH + jout], lg0);
          lg1 = fmaf(hv, Wcls[(size_t)524288 + (size_t)t * NH + jout], lg1);
          if (s == NT) out[64 + 32768 + (size_t)b * NH + jout] = hv;
        } else if (s == NT - 1) {
          out[64 + (size_t)b * NH + jout] = hv;
        }
      }
    }
    gbar(c1, c2, g, (unsigned)(s + 1));
  }

  // ---- epilogue: classifier reduction ----
  if (isL1 && tid < 256) {
    part[tid] = lg0;
    part[256 + tid] = lg1;
  }
  __syncthreads();
  if (isL1 && tid < 64) {
    const int c = tid >> 5, bb = tid & 31;
    float v = 0.f;
    #pragma unroll
    for (int ji = 0; ji < 8; ++ji) v += part[c * 256 + ji * 32 + bb];
    st_coh(&plog[(size_t)(bid - 128) * 64 + c * 32 + bb], v);
  }
  gbar(c1, c2, g, (unsigned)(NT + 2));
  if (bid == 0 && tid < 64) {
    const int c = tid >> 5, bb = tid & 31;
    float v = bcls[c];
    for (int blk = 0; blk < 128; ++blk)
      v += ld_cohf(&plog[(size_t)blk * 64 + c * 32 + bb]);
    out[(size_t)bb * 2 + c] = v;  // logits [B,C]
  }
}

extern "C" void kernel_launch(void* const* d_in, const int* in_sizes, int n_in,
                              void* d_out, int out_size, void* d_ws, size_t ws_size,
                              hipStream_t stream) {
  const float* x    = (const float*)d_in[0];
  const float* h0   = (const float*)d_in[1];
  const float* Wih0 = (const float*)d_in[2];
  const float* Whh0 = (const float*)d_in[3];
  const float* bih0 = (const float*)d_in[4];
  const float* bhh0 = (const float*)d_in[5];
  const float* Wih1 = (const float*)d_in[6];
  const float* Whh1 = (const float*)d_in[7];
  const float* bih1 = (const float*)d_in[8];
  const float* bhh1 = (const float*)d_in[9];
  const float* Wcls = (const float*)d_in[10];
  const float* bcls = (const float*)d_in[11];
  float* out = (float*)d_out;
  float* ws  = (float*)d_ws;

  int use_x4 = (ws_size >= ((size_t)X4OFF + X4FLOATS) * 4) ? 1 : 0;

  hipLaunchKernelGGL(init_kernel, dim3(256), dim3(256), 0, stream, h0, ws);
  if (use_x4)
    hipLaunchKernelGGL(xpose_kernel, dim3(512), dim3(256), 0, stream, x, ws);

  void* args[] = { (void*)&x, (void*)&Wih0, (void*)&Whh0, (void*)&bih0, (void*)&bhh0,
                   (void*)&Wih1, (void*)&Whh1, (void*)&bih1, (void*)&bhh1,
                   (void*)&Wcls, (void*)&bcls, (void*)&out, (void*)&ws, (void*)&use_x4 };
  hipLaunchCooperativeKernel((void*)rnn_kernel, dim3(256), dim3(512), args, 0, stream);
}